// Round 1
// baseline (3430.305 us; speedup 1.0000x reference)
//
#include <hip/hip_runtime.h>
#include <math.h>

// Mamba forward, MI355X. Round 0: correctness-first, all fp32.
// Dims
#define DM    768
#define DS    16
#define DI    1536
#define DTR   48
#define NB    2
#define NL    1024
#define NBL   (NB*NL)
#define NVOC  32000

static __device__ __forceinline__ float siluf(float x){ return x / (1.0f + expf(-x)); }
static __device__ __forceinline__ float softplusf(float x){ return (x > 20.0f) ? x : log1pf(expf(x)); }

// ---------------- embedding gather ----------------
__global__ __launch_bounds__(256) void embed_kernel(const int* __restrict__ ids,
        const float* __restrict__ emb, float* __restrict__ x){
    int i = blockIdx.x*256 + threadIdx.x;
    if (i >= NBL*DM) return;
    int row = i / DM, c = i - row*DM;
    x[i] = emb[(size_t)ids[row]*DM + c];
}

// ---------------- rmsnorm (one block per row) ----------------
__global__ __launch_bounds__(256) void rmsnorm_kernel(const float* __restrict__ x,
        const float* __restrict__ w, float* __restrict__ h){
    int row = blockIdx.x;
    const float* xr = x + (size_t)row*DM;
    __shared__ float red[256];
    float s = 0.f;
    for (int c = threadIdx.x; c < DM; c += 256){ float v = xr[c]; s += v*v; }
    red[threadIdx.x] = s; __syncthreads();
    for (int o = 128; o > 0; o >>= 1){
        if (threadIdx.x < o) red[threadIdx.x] += red[threadIdx.x + o];
        __syncthreads();
    }
    float r = 1.0f / sqrtf(red[0]*(1.0f/DM) + 1e-5f);
    for (int c = threadIdx.x; c < DM; c += 256) h[(size_t)row*DM + c] = xr[c]*r*w[c];
}

// ---------------- tiled fp32 GEMM: C[M,N] = A[M,K] * Bw[N,K]^T ----------------
// act: 0=none, 1=softplus.  accum: C += result instead of C = result.
__global__ __launch_bounds__(256) void gemm_nt(const float* __restrict__ A,
        const float* __restrict__ Bw, float* __restrict__ C, const float* __restrict__ bias,
        int M, int N, int K, int lda, int ldb, int ldc, int act, int accum){
    __shared__ float As[16][68];
    __shared__ float Bs[16][68];
    int tid = threadIdx.x;
    int tn = tid & 15, tm = tid >> 4;
    int n0 = blockIdx.x * 64, m0 = blockIdx.y * 64;
    float acc[4][4] = {{0.f}};
    for (int kt = 0; kt < K; kt += 16){
        int gk = kt + tn;            // lane-varying k -> coalesced along K
        bool kok = gk < K;
        #pragma unroll
        for (int r = 0; r < 4; r++){
            int m = tm + r*16;
            As[tn][m] = (kok && (m0 + m) < M) ? A[(size_t)(m0+m)*lda + gk] : 0.f;
            Bs[tn][m] = (kok && (n0 + m) < N) ? Bw[(size_t)(n0+m)*ldb + gk] : 0.f;
        }
        __syncthreads();
        #pragma unroll
        for (int kk = 0; kk < 16; kk++){
            float a0 = As[kk][tm*4+0], a1 = As[kk][tm*4+1], a2 = As[kk][tm*4+2], a3 = As[kk][tm*4+3];
            float b0 = Bs[kk][tn*4+0], b1 = Bs[kk][tn*4+1], b2 = Bs[kk][tn*4+2], b3 = Bs[kk][tn*4+3];
            acc[0][0] += a0*b0; acc[0][1] += a0*b1; acc[0][2] += a0*b2; acc[0][3] += a0*b3;
            acc[1][0] += a1*b0; acc[1][1] += a1*b1; acc[1][2] += a1*b2; acc[1][3] += a1*b3;
            acc[2][0] += a2*b0; acc[2][1] += a2*b1; acc[2][2] += a2*b2; acc[2][3] += a2*b3;
            acc[3][0] += a3*b0; acc[3][1] += a3*b1; acc[3][2] += a3*b2; acc[3][3] += a3*b3;
        }
        __syncthreads();
    }
    #pragma unroll
    for (int i = 0; i < 4; i++){
        int gm = m0 + tm*4 + i;
        if (gm >= M) continue;
        #pragma unroll
        for (int j = 0; j < 4; j++){
            int gn = n0 + tn*4 + j;
            if (gn >= N) continue;
            float v = acc[i][j];
            if (bias) v += bias[gn];
            if (act == 1) v = softplusf(v);
            size_t ci = (size_t)gm*ldc + gn;
            if (accum) v += C[ci];
            C[ci] = v;
        }
    }
}

// ---------------- depthwise causal conv (k=4) + bias + silu ----------------
__global__ __launch_bounds__(256) void conv_silu_kernel(const float* __restrict__ xz,
        const float* __restrict__ cw, const float* __restrict__ cb, float* __restrict__ xs){
    int i = blockIdx.x*256 + threadIdx.x;
    if (i >= NBL*DI) return;
    int bl = i / DI, d = i - bl*DI;
    int l = bl & (NL-1);
    float acc = cb[d];
    #pragma unroll
    for (int j = 0; j < 4; j++){
        int off = j - 3;
        if (l + off >= 0) acc += cw[d*4+j] * xz[(size_t)(bl + off)*(2*DI) + d];
    }
    xs[i] = siluf(acc);
}

// ---------------- transpose: out[C,R] = in[R,C]^T ----------------
__global__ __launch_bounds__(256) void transpose_kernel(const float* __restrict__ in,
        float* __restrict__ out, int R, int Ccols){
    __shared__ float tile[32][33];
    int c0 = blockIdx.x*32, r0 = blockIdx.y*32;
    int tx = threadIdx.x & 31, ty = threadIdx.x >> 5;  // 32x8
    #pragma unroll
    for (int i = 0; i < 32; i += 8){
        int r = r0 + ty + i, c = c0 + tx;
        tile[ty+i][tx] = (r < R && c < Ccols) ? in[(size_t)r*Ccols + c] : 0.f;
    }
    __syncthreads();
    #pragma unroll
    for (int i = 0; i < 32; i += 8){
        int r = r0 + tx, c = c0 + ty + i;
        if (c < Ccols && r < R) out[(size_t)c*R + r] = tile[tx][ty+i];
    }
}

// ---------------- block-wide exclusive prefix sum (256 threads) ----------------
static __device__ __forceinline__ float block_scan_excl(float v, float* sbuf, float* total){
    int tid = threadIdx.x;
    sbuf[tid] = v;
    __syncthreads();
    float run = v;
    #pragma unroll
    for (int s = 1; s < 256; s <<= 1){
        float add = (tid >= s) ? sbuf[tid - s] : 0.0f;
        __syncthreads();
        run += add;
        sbuf[tid] = run;
        __syncthreads();
    }
    float t = sbuf[255];
    __syncthreads();              // protect sbuf for next reuse
    *total = t;
    return run - v;
}

// ---------------- selective scan, replicating reference numerics ----------------
// One block per (b,d). Inputs in d-major (transposed) layout for coalescing.
// e[l] = exp(A_n * (T - pdt[l])), pdt = inclusive prefix of dt (matches the
// reference's exp(reverse-cumsum of shifted dA)). x = cumsum(dt*u*B*e)/(e+1e-12).
__global__ __launch_bounds__(256) void scan_kernel(const float* __restrict__ u_t,
        const float* __restrict__ dt_t, const float* __restrict__ xdbl_t,
        const float* __restrict__ A_log, const float* __restrict__ Dp,
        float* __restrict__ y_t){
    __shared__ float sbuf[256];
    int tid = threadIdx.x;
    int bd = blockIdx.x;
    int b = bd / DI, d = bd - b*DI;
    size_t rowoff = (size_t)d*NBL + b*NL;
    int l0 = tid*4;

    float4 dtv = *(const float4*)(dt_t + rowoff + l0);
    float4 uv  = *(const float4*)(u_t  + rowoff + l0);
    float d4[4] = {dtv.x, dtv.y, dtv.z, dtv.w};
    float u4[4] = {uv.x,  uv.y,  uv.z,  uv.w};
    float pl[4], du[4], yac[4] = {0.f,0.f,0.f,0.f};
    float run = 0.f;
    #pragma unroll
    for (int r = 0; r < 4; r++){ run += d4[r]; pl[r] = run; du[r] = d4[r]*u4[r]; }
    float T;
    float ex = block_scan_excl(run, sbuf, &T);
    #pragma unroll
    for (int r = 0; r < 4; r++) pl[r] += ex;   // global inclusive prefix of dt

    for (int n = 0; n < DS; n++){
        float An = -expf(A_log[d*DS + n]);
        float4 Bv4 = *(const float4*)(xdbl_t + (size_t)(DTR+n)*NBL + b*NL + l0);
        float4 Cv4 = *(const float4*)(xdbl_t + (size_t)(DTR+DS+n)*NBL + b*NL + l0);
        float Bv[4] = {Bv4.x, Bv4.y, Bv4.z, Bv4.w};
        float Cv[4] = {Cv4.x, Cv4.y, Cv4.z, Cv4.w};
        float e[4], zl[4];
        float zrun = 0.f;
        #pragma unroll
        for (int r = 0; r < 4; r++){
            e[r] = expf(An * (T - pl[r]));       // underflows to 0 exactly like ref
            zrun += du[r]*Bv[r]*e[r];
            zl[r] = zrun;
        }
        float zt;
        float zex = block_scan_excl(zrun, sbuf, &zt);
        #pragma unroll
        for (int r = 0; r < 4; r++){
            float num = zex + zl[r];
            float xv  = num / (e[r] + 1e-12f);
            yac[r] += xv * Cv[r];
        }
    }
    float Dv = Dp[d];
    float4 yo;
    yo.x = yac[0] + u4[0]*Dv;
    yo.y = yac[1] + u4[1]*Dv;
    yo.z = yac[2] + u4[2]*Dv;
    yo.w = yac[3] + u4[3]*Dv;
    *(float4*)(y_t + rowoff + l0) = yo;
}

// ---------------- transpose y back + gate with silu(res) ----------------
__global__ __launch_bounds__(256) void gate_transpose_kernel(const float* __restrict__ y_t,
        const float* __restrict__ xz, float* __restrict__ ys){
    __shared__ float tile[32][33];
    int c0 = blockIdx.x*32;   // bl tile
    int r0 = blockIdx.y*32;   // d tile
    int tx = threadIdx.x & 31, ty = threadIdx.x >> 5;
    #pragma unroll
    for (int i = 0; i < 32; i += 8)
        tile[ty+i][tx] = y_t[(size_t)(r0+ty+i)*NBL + (c0+tx)];
    __syncthreads();
    #pragma unroll
    for (int i = 0; i < 32; i += 8){
        int d  = r0 + tx;
        int bl = c0 + ty + i;
        float g = siluf(xz[(size_t)bl*(2*DI) + DI + d]);
        ys[(size_t)bl*DI + d] = tile[tx][ty+i] * g;
    }
}

extern "C" void kernel_launch(void* const* d_in, const int* in_sizes, int n_in,
                              void* d_out, int out_size, void* d_ws, size_t ws_size,
                              hipStream_t stream){
    const int*   ids    = (const int*)d_in[0];
    const float* emb    = (const float*)d_in[1];
    const float* W_in   = (const float*)d_in[2];
    const float* convw  = (const float*)d_in[3];
    const float* convb  = (const float*)d_in[4];
    const float* xproj  = (const float*)d_in[5];
    const float* dtw    = (const float*)d_in[6];
    const float* dtbias = (const float*)d_in[7];
    const float* Alog   = (const float*)d_in[8];
    const float* Dpar   = (const float*)d_in[9];
    const float* Wout   = (const float*)d_in[10];
    const float* normw  = (const float*)d_in[11];
    const float* normf  = (const float*)d_in[12];
    float* out = (float*)d_out;

    // workspace layout (floats); total 25,493,504 floats ~= 97.3 MB
    float* ws    = (float*)d_ws;
    float* x     = ws;                  // NBL*DM
    float* h     = x     + (size_t)NBL*DM;
    float* xz    = h     + (size_t)NBL*DM;      // NBL*2*DI
    float* xs    = xz    + (size_t)NBL*2*DI;    // NBL*DI
    float* xdbl  = xs    + (size_t)NBL*DI;      // NBL*80
    float* xdblt = xdbl  + (size_t)NBL*80;      // 80*NBL
    float* dtb   = xdblt + (size_t)NBL*80;      // NBL*DI (reused as ys after scan)
    float* dtt   = dtb   + (size_t)NBL*DI;      // DI*NBL
    float* ut    = dtt   + (size_t)NBL*DI;      // DI*NBL
    float* yt    = ut    + (size_t)NBL*DI;      // DI*NBL

    embed_kernel<<<(NBL*DM + 255)/256, 256, 0, stream>>>(ids, emb, x);

    for (int i = 0; i < 2; i++){
        rmsnorm_kernel<<<NBL, 256, 0, stream>>>(x, normw + i*DM, h);
        // xz = h @ W_in^T   (2048 x 3072, K=768)
        gemm_nt<<<dim3(48,32), 256, 0, stream>>>(h, W_in + (size_t)i*2*DI*DM, xz, nullptr,
                NBL, 2*DI, DM, DM, DM, 2*DI, 0, 0);
        // xs = silu(causal depthwise conv(xz[:, :DI]) + b)
        conv_silu_kernel<<<(NBL*DI + 255)/256, 256, 0, stream>>>(xz, convw + i*DI*4, convb + i*DI, xs);
        // xdbl = xs @ x_proj^T   (2048 x 80, K=1536)
        gemm_nt<<<dim3(2,32), 256, 0, stream>>>(xs, xproj + (size_t)i*80*DI, xdbl, nullptr,
                NBL, 80, DI, DI, DI, 80, 0, 0);
        // dt = softplus(xdbl[:, :48] @ dt_proj^T + dt_bias)   (2048 x 1536, K=48)
        gemm_nt<<<dim3(24,32), 256, 0, stream>>>(xdbl, dtw + (size_t)i*DI*DTR, dtb, dtbias + i*DI,
                NBL, DI, DTR, 80, DTR, DI, 1, 0);
        // transposes for coalesced scan
        transpose_kernel<<<dim3(3,64),  256, 0, stream>>>(xdbl, xdblt, NBL, 80);
        transpose_kernel<<<dim3(48,64), 256, 0, stream>>>(dtb,  dtt,   NBL, DI);
        transpose_kernel<<<dim3(48,64), 256, 0, stream>>>(xs,   ut,    NBL, DI);
        // selective scan (reference-numerics)
        scan_kernel<<<NB*DI, 256, 0, stream>>>(ut, dtt, xdblt,
                Alog + (size_t)i*DI*DS, Dpar + i*DI, yt);
        // ys = y * silu(res), transposed back to (bl, d); ys aliases dtb
        gate_transpose_kernel<<<dim3(64,48), 256, 0, stream>>>(yt, xz, dtb);
        // x += ys @ W_out^T   (2048 x 768, K=1536), residual accumulate
        gemm_nt<<<dim3(12,32), 256, 0, stream>>>(dtb, Wout + (size_t)i*DM*DI, x, nullptr,
                NBL, DM, DI, DI, DI, DM, 0, 1);
    }

    rmsnorm_kernel<<<NBL, 256, 0, stream>>>(x, normf, h);
    // logits = h @ emb^T   (2048 x 32000, K=768)
    gemm_nt<<<dim3(500,32), 256, 0, stream>>>(h, emb, out, nullptr,
            NBL, NVOC, DM, DM, DM, NVOC, 0, 0);
}

// Round 2
// 1361.678 us; speedup vs baseline: 2.5192x; 2.5192x over previous
//
#include <hip/hip_runtime.h>
#include <math.h>

// Mamba forward, MI355X. Round 1: bf16 MFMA for the three big GEMMs
// (W_in, W_out, logits); fp32 gemm_nt kept for x_proj (N=80) / dt_proj (K=48).
#define DM    768
#define DS    16
#define DI    1536
#define DTR   48
#define NB    2
#define NL    1024
#define NBL   (NB*NL)
#define NVOC  32000

typedef __attribute__((ext_vector_type(8))) short bf16x8;   // 8 bf16 in 4 VGPRs
typedef __attribute__((ext_vector_type(4))) float floatx4;

static __device__ __forceinline__ float siluf(float x){ return x / (1.0f + expf(-x)); }
static __device__ __forceinline__ float softplusf(float x){ return (x > 20.0f) ? x : log1pf(expf(x)); }
static __device__ __forceinline__ unsigned short f2bf(float f){
    unsigned int u = __float_as_uint(f);
    u += 0x7FFFu + ((u >> 16) & 1u);          // RNE
    return (unsigned short)(u >> 16);
}

#define GLL16(g, l) __builtin_amdgcn_global_load_lds( \
    (const __attribute__((address_space(1))) unsigned int*)(g), \
    (__attribute__((address_space(3))) unsigned int*)(l), 16, 0, 0)

// ---------------- fp32 -> bf16 cast (n multiple of 4) ----------------
__global__ __launch_bounds__(256) void cast_bf16_kernel(const float* __restrict__ in,
        unsigned short* __restrict__ out, int n4){
    int i = blockIdx.x*256 + threadIdx.x;
    if (i >= n4) return;
    float4 v = ((const float4*)in)[i];
    ushort4 o = { f2bf(v.x), f2bf(v.y), f2bf(v.z), f2bf(v.w) };
    ((ushort4*)out)[i] = o;
}

// ---------------- embedding gather ----------------
__global__ __launch_bounds__(256) void embed_kernel(const int* __restrict__ ids,
        const float* __restrict__ emb, float* __restrict__ x){
    int i = blockIdx.x*256 + threadIdx.x;
    if (i >= NBL*DM) return;
    int row = i / DM, c = i - row*DM;
    x[i] = emb[(size_t)ids[row]*DM + c];
}

// ---------------- rmsnorm -> bf16 output ----------------
__global__ __launch_bounds__(256) void rmsnorm_bf16_kernel(const float* __restrict__ x,
        const float* __restrict__ w, unsigned short* __restrict__ h){
    int row = blockIdx.x;
    const float* xr = x + (size_t)row*DM;
    __shared__ float red[256];
    float s = 0.f;
    for (int c = threadIdx.x; c < DM; c += 256){ float v = xr[c]; s += v*v; }
    red[threadIdx.x] = s; __syncthreads();
    for (int o = 128; o > 0; o >>= 1){
        if (threadIdx.x < o) red[threadIdx.x] += red[threadIdx.x + o];
        __syncthreads();
    }
    float r = 1.0f / sqrtf(red[0]*(1.0f/DM) + 1e-5f);
    for (int c = threadIdx.x; c < DM; c += 256) h[(size_t)row*DM + c] = f2bf(xr[c]*r*w[c]);
}

// ---------------- bf16 MFMA GEMM: C[M,N](f32) = A[M,K]bf16 * B[N,K]bf16^T ----
// Requires M%128==0, N%128==0, K%32==0. lda=ldb=K, ldc=N.
// m97-style: 128x128 tile, BK=32, global_load_lds width-16 staging,
// 4 waves each computing 64x64 via 4x4 grid of 16x16x32 MFMA.
template<int ACCUM>
__global__ __launch_bounds__(256) void mfma_gemm_nt(const unsigned short* __restrict__ A,
        const unsigned short* __restrict__ B, float* __restrict__ C,
        int M, int N, int K){
    __shared__ __align__(16) unsigned short Asm[128*32];
    __shared__ __align__(16) unsigned short Bsm[128*32];
    int tid = threadIdx.x;
    int m0 = blockIdx.y * 128, n0 = blockIdx.x * 128;
    int lane = tid & 63;
    int quad = lane >> 4, l16 = lane & 15;
    int wave = tid >> 6;
    int wm = (wave >> 1) * 64, wn = (wave & 1) * 64;

    floatx4 acc[4][4] = {};

    // staging: lane (tid) loads 16B: row=tid>>2 (0..63), kcol=(tid&3)*8
    int srow = tid >> 2, skcol = (tid & 3) * 8;
    const unsigned short* Ag = A + (size_t)(m0 + srow) * K + skcol;
    const unsigned short* Bg = B + (size_t)(n0 + srow) * K + skcol;
    size_t half = (size_t)64 * K;

    for (int kt = 0; kt < K; kt += 32){
        // LDS dest: per-lane tid*16B — HW uses wave-uniform base + lane*16,
        // which matches the unpadded [128][32]-ushort row-major layout exactly.
        GLL16(Ag + kt,        &Asm[(size_t)tid*8]);
        GLL16(Ag + kt + half, &Asm[2048 + (size_t)tid*8]);
        GLL16(Bg + kt,        &Bsm[(size_t)tid*8]);
        GLL16(Bg + kt + half, &Bsm[2048 + (size_t)tid*8]);
        __syncthreads();   // compiler drains vmcnt before s_barrier

        bf16x8 af[4], bff[4];
        #pragma unroll
        for (int i = 0; i < 4; i++){
            af[i]  = *(const bf16x8*)&Asm[(wm + i*16 + l16)*32 + quad*8];
            bff[i] = *(const bf16x8*)&Bsm[(wn + i*16 + l16)*32 + quad*8];
        }
        #pragma unroll
        for (int i = 0; i < 4; i++)
            #pragma unroll
            for (int j = 0; j < 4; j++)
                acc[i][j] = __builtin_amdgcn_mfma_f32_16x16x32_bf16(af[i], bff[j], acc[i][j], 0, 0, 0);
        __syncthreads();
    }

    // C/D layout: col = lane&15, row = quad*4 + reg   [m89-verified mapping]
    #pragma unroll
    for (int i = 0; i < 4; i++){
        int gm = m0 + wm + i*16 + quad*4;
        #pragma unroll
        for (int j = 0; j < 4; j++){
            int gn = n0 + wn + j*16 + l16;
            float* cp = C + (size_t)gm*N + gn;
            #pragma unroll
            for (int r = 0; r < 4; r++){
                float v = acc[i][j][r];
                if (ACCUM) v += cp[(size_t)r*N];
                cp[(size_t)r*N] = v;
            }
        }
    }
}

// ---------------- fp32 tiled GEMM (small shapes): C = A * Bw^T ----------------
__global__ __launch_bounds__(256) void gemm_nt(const float* __restrict__ A,
        const float* __restrict__ Bw, float* __restrict__ C, const float* __restrict__ bias,
        int M, int N, int K, int lda, int ldb, int ldc, int act, int accum){
    __shared__ float As[16][68];
    __shared__ float Bs[16][68];
    int tid = threadIdx.x;
    int tn = tid & 15, tm = tid >> 4;
    int n0 = blockIdx.x * 64, m0 = blockIdx.y * 64;
    float acc[4][4] = {{0.f}};
    for (int kt = 0; kt < K; kt += 16){
        int gk = kt + tn;
        bool kok = gk < K;
        #pragma unroll
        for (int r = 0; r < 4; r++){
            int m = tm + r*16;
            As[tn][m] = (kok && (m0 + m) < M) ? A[(size_t)(m0+m)*lda + gk] : 0.f;
            Bs[tn][m] = (kok && (n0 + m) < N) ? Bw[(size_t)(n0+m)*ldb + gk] : 0.f;
        }
        __syncthreads();
        #pragma unroll
        for (int kk = 0; kk < 16; kk++){
            float a0 = As[kk][tm*4+0], a1 = As[kk][tm*4+1], a2 = As[kk][tm*4+2], a3 = As[kk][tm*4+3];
            float b0 = Bs[kk][tn*4+0], b1 = Bs[kk][tn*4+1], b2 = Bs[kk][tn*4+2], b3 = Bs[kk][tn*4+3];
            acc[0][0] += a0*b0; acc[0][1] += a0*b1; acc[0][2] += a0*b2; acc[0][3] += a0*b3;
            acc[1][0] += a1*b0; acc[1][1] += a1*b1; acc[1][2] += a1*b2; acc[1][3] += a1*b3;
            acc[2][0] += a2*b0; acc[2][1] += a2*b1; acc[2][2] += a2*b2; acc[2][3] += a2*b3;
            acc[3][0] += a3*b0; acc[3][1] += a3*b1; acc[3][2] += a3*b2; acc[3][3] += a3*b3;
        }
        __syncthreads();
    }
    #pragma unroll
    for (int i = 0; i < 4; i++){
        int gm = m0 + tm*4 + i;
        if (gm >= M) continue;
        #pragma unroll
        for (int j = 0; j < 4; j++){
            int gn = n0 + tn*4 + j;
            if (gn >= N) continue;
            float v = acc[i][j];
            if (bias) v += bias[gn];
            if (act == 1) v = softplusf(v);
            size_t ci = (size_t)gm*ldc + gn;
            if (accum) v += C[ci];
            C[ci] = v;
        }
    }
}

// ---------------- depthwise causal conv (k=4) + bias + silu ----------------
__global__ __launch_bounds__(256) void conv_silu_kernel(const float* __restrict__ xz,
        const float* __restrict__ cw, const float* __restrict__ cb, float* __restrict__ xs){
    int i = blockIdx.x*256 + threadIdx.x;
    if (i >= NBL*DI) return;
    int bl = i / DI, d = i - bl*DI;
    int l = bl & (NL-1);
    float acc = cb[d];
    #pragma unroll
    for (int j = 0; j < 4; j++){
        int off = j - 3;
        if (l + off >= 0) acc += cw[d*4+j] * xz[(size_t)(bl + off)*(2*DI) + d];
    }
    xs[i] = siluf(acc);
}

// ---------------- transpose: out[C,R] = in[R,C]^T ----------------
__global__ __launch_bounds__(256) void transpose_kernel(const float* __restrict__ in,
        float* __restrict__ out, int R, int Ccols){
    __shared__ float tile[32][33];
    int c0 = blockIdx.x*32, r0 = blockIdx.y*32;
    int tx = threadIdx.x & 31, ty = threadIdx.x >> 5;
    #pragma unroll
    for (int i = 0; i < 32; i += 8){
        int r = r0 + ty + i, c = c0 + tx;
        tile[ty+i][tx] = (r < R && c < Ccols) ? in[(size_t)r*Ccols + c] : 0.f;
    }
    __syncthreads();
    #pragma unroll
    for (int i = 0; i < 32; i += 8){
        int r = r0 + tx, c = c0 + ty + i;
        if (c < Ccols && r < R) out[(size_t)c*R + r] = tile[tx][ty+i];
    }
}

// ---------------- block-wide exclusive prefix sum (256 threads) ----------------
static __device__ __forceinline__ float block_scan_excl(float v, float* sbuf, float* total){
    int tid = threadIdx.x;
    sbuf[tid] = v;
    __syncthreads();
    float run = v;
    #pragma unroll
    for (int s = 1; s < 256; s <<= 1){
        float add = (tid >= s) ? sbuf[tid - s] : 0.0f;
        __syncthreads();
        run += add;
        sbuf[tid] = run;
        __syncthreads();
    }
    float t = sbuf[255];
    __syncthreads();
    *total = t;
    return run - v;
}

// ---------------- selective scan (reference numerics) ----------------
// y_t may alias dt_t (per-block row exclusivity; reads precede writes).
__global__ __launch_bounds__(256) void scan_kernel(const float* __restrict__ u_t,
        const float* dt_t, const float* __restrict__ xdbl_t,
        const float* __restrict__ A_log, const float* __restrict__ Dp,
        float* y_t){
    __shared__ float sbuf[256];
    int tid = threadIdx.x;
    int bd = blockIdx.x;
    int b = bd / DI, d = bd - b*DI;
    size_t rowoff = (size_t)d*NBL + b*NL;
    int l0 = tid*4;

    float4 dtv = *(const float4*)(dt_t + rowoff + l0);
    float4 uv  = *(const float4*)(u_t  + rowoff + l0);
    float d4[4] = {dtv.x, dtv.y, dtv.z, dtv.w};
    float u4[4] = {uv.x,  uv.y,  uv.z,  uv.w};
    float pl[4], du[4], yac[4] = {0.f,0.f,0.f,0.f};
    float run = 0.f;
    #pragma unroll
    for (int r = 0; r < 4; r++){ run += d4[r]; pl[r] = run; du[r] = d4[r]*u4[r]; }
    float T;
    float ex = block_scan_excl(run, sbuf, &T);
    #pragma unroll
    for (int r = 0; r < 4; r++) pl[r] += ex;

    for (int n = 0; n < DS; n++){
        float An = -expf(A_log[d*DS + n]);
        float4 Bv4 = *(const float4*)(xdbl_t + (size_t)(DTR+n)*NBL + b*NL + l0);
        float4 Cv4 = *(const float4*)(xdbl_t + (size_t)(DTR+DS+n)*NBL + b*NL + l0);
        float Bv[4] = {Bv4.x, Bv4.y, Bv4.z, Bv4.w};
        float Cv[4] = {Cv4.x, Cv4.y, Cv4.z, Cv4.w};
        float e[4], zl[4];
        float zrun = 0.f;
        #pragma unroll
        for (int r = 0; r < 4; r++){
            e[r] = expf(An * (T - pl[r]));
            zrun += du[r]*Bv[r]*e[r];
            zl[r] = zrun;
        }
        float zt;
        float zex = block_scan_excl(zrun, sbuf, &zt);
        #pragma unroll
        for (int r = 0; r < 4; r++){
            float num = zex + zl[r];
            float xv  = num / (e[r] + 1e-12f);
            yac[r] += xv * Cv[r];
        }
    }
    float Dv = Dp[d];
    float4 yo;
    yo.x = yac[0] + u4[0]*Dv;
    yo.y = yac[1] + u4[1]*Dv;
    yo.z = yac[2] + u4[2]*Dv;
    yo.w = yac[3] + u4[3]*Dv;
    *(float4*)(y_t + rowoff + l0) = yo;
}

// ---------------- transpose y back + gate with silu(res), bf16 output --------
__global__ __launch_bounds__(256) void gate_transpose_kernel(const float* __restrict__ y_t,
        const float* __restrict__ xz, unsigned short* __restrict__ ys){
    __shared__ float tile[32][33];
    int c0 = blockIdx.x*32;   // bl tile
    int r0 = blockIdx.y*32;   // d tile
    int tx = threadIdx.x & 31, ty = threadIdx.x >> 5;
    #pragma unroll
    for (int i = 0; i < 32; i += 8)
        tile[ty+i][tx] = y_t[(size_t)(r0+ty+i)*NBL + (c0+tx)];
    __syncthreads();
    #pragma unroll
    for (int i = 0; i < 32; i += 8){
        int d  = r0 + tx;
        int bl = c0 + ty + i;
        float g = siluf(xz[(size_t)bl*(2*DI) + DI + d]);
        ys[(size_t)bl*DI + d] = f2bf(tile[tx][ty+i] * g);
    }
}

extern "C" void kernel_launch(void* const* d_in, const int* in_sizes, int n_in,
                              void* d_out, int out_size, void* d_ws, size_t ws_size,
                              hipStream_t stream){
    const int*   ids    = (const int*)d_in[0];
    const float* emb    = (const float*)d_in[1];
    const float* W_in   = (const float*)d_in[2];
    const float* convw  = (const float*)d_in[3];
    const float* convb  = (const float*)d_in[4];
    const float* xproj  = (const float*)d_in[5];
    const float* dtw    = (const float*)d_in[6];
    const float* dtbias = (const float*)d_in[7];
    const float* Alog   = (const float*)d_in[8];
    const float* Dpar   = (const float*)d_in[9];
    const float* Wout   = (const float*)d_in[10];
    const float* normw  = (const float*)d_in[11];
    const float* normf  = (const float*)d_in[12];
    float* out = (float*)d_out;

    // ---- workspace layout ----
    float* ws    = (float*)d_ws;
    float* x     = ws;                              // NBL*DM f32
    float* xz    = x     + (size_t)NBL*DM;          // NBL*2*DI f32
    float* xs    = xz    + (size_t)NBL*2*DI;        // NBL*DI f32
    float* xdbl  = xs    + (size_t)NBL*DI;          // NBL*80 f32
    float* xdblt = xdbl  + (size_t)NBL*80;          // 80*NBL f32
    float* dtb   = xdblt + (size_t)NBL*80;          // NBL*DI f32 (later: ys_bf as ushort)
    float* dtt   = dtb   + (size_t)NBL*DI;          // DI*NBL f32 (scan writes y here too)
    float* ut    = dtt   + (size_t)NBL*DI;          // DI*NBL f32
    unsigned short* h_bf   = (unsigned short*)(ut + (size_t)NBL*DI);   // NBL*DM
    unsigned short* emb_bf = h_bf   + (size_t)NBL*DM;                  // NVOC*DM
    unsigned short* win_bf = emb_bf + (size_t)NVOC*DM;                 // 2*2*DI*DM
    unsigned short* wout_bf= win_bf + (size_t)2*2*DI*DM;               // 2*DM*DI
    unsigned short* ys_bf  = (unsigned short*)dtb;
    float* yt = dtt;   // alias: scan writes y over dt (row-exclusive, safe)

    // ---- weight / emb casts (every call; ws is re-poisoned by harness) ----
    cast_bf16_kernel<<<(NVOC*DM/4 + 255)/256, 256, 0, stream>>>(emb, emb_bf, NVOC*DM/4);
    cast_bf16_kernel<<<(2*2*DI*DM/4 + 255)/256, 256, 0, stream>>>(W_in, win_bf, 2*2*DI*DM/4);
    cast_bf16_kernel<<<(2*DM*DI/4 + 255)/256, 256, 0, stream>>>(Wout, wout_bf, 2*DM*DI/4);

    embed_kernel<<<(NBL*DM + 255)/256, 256, 0, stream>>>(ids, emb, x);

    for (int i = 0; i < 2; i++){
        rmsnorm_bf16_kernel<<<NBL, 256, 0, stream>>>(x, normw + i*DM, h_bf);
        // xz = h @ W_in^T   (2048 x 3072, K=768) — bf16 MFMA
        mfma_gemm_nt<0><<<dim3(3072/128, NBL/128), 256, 0, stream>>>(
                h_bf, win_bf + (size_t)i*2*DI*DM, xz, NBL, 2*DI, DM);
        conv_silu_kernel<<<(NBL*DI + 255)/256, 256, 0, stream>>>(xz, convw + i*DI*4, convb + i*DI, xs);
        // xdbl = xs @ x_proj^T   (2048 x 80, K=1536) — fp32
        gemm_nt<<<dim3(2,32), 256, 0, stream>>>(xs, xproj + (size_t)i*80*DI, xdbl, nullptr,
                NBL, 80, DI, DI, DI, 80, 0, 0);
        // dt = softplus(xdbl[:, :48] @ dt_proj^T + bias)   (2048 x 1536, K=48) — fp32
        gemm_nt<<<dim3(24,32), 256, 0, stream>>>(xdbl, dtw + (size_t)i*DI*DTR, dtb, dtbias + i*DI,
                NBL, DI, DTR, 80, DTR, DI, 1, 0);
        transpose_kernel<<<dim3(3,64),  256, 0, stream>>>(xdbl, xdblt, NBL, 80);
        transpose_kernel<<<dim3(48,64), 256, 0, stream>>>(dtb,  dtt,   NBL, DI);
        transpose_kernel<<<dim3(48,64), 256, 0, stream>>>(xs,   ut,    NBL, DI);
        scan_kernel<<<NB*DI, 256, 0, stream>>>(ut, dtt, xdblt,
                Alog + (size_t)i*DI*DS, Dpar + i*DI, yt);
        gate_transpose_kernel<<<dim3(64,48), 256, 0, stream>>>(yt, xz, ys_bf);
        // x += ys @ W_out^T   (2048 x 768, K=1536) — bf16 MFMA, accumulate
        mfma_gemm_nt<1><<<dim3(DM/128, NBL/128), 256, 0, stream>>>(
                ys_bf, wout_bf + (size_t)i*DM*DI, x, NBL, DM, DI);
    }

    rmsnorm_bf16_kernel<<<NBL, 256, 0, stream>>>(x, normf, h_bf);
    // logits = h @ emb^T   (2048 x 32000, K=768) — bf16 MFMA
    mfma_gemm_nt<0><<<dim3(NVOC/128, NBL/128), 256, 0, stream>>>(
            h_bf, emb_bf, out, NBL, NVOC, DM);
}